// Round 1
// baseline (87.266 us; speedup 1.0000x reference)
//
#include <hip/hip_runtime.h>
#include <math.h>

// Problem constants
#define B_    16
#define O_    16
#define NPERM 240          // O*(O-1)
#define NUM_IN 160         // P0 + 2*P1 + 2*P2 = 32+64+64
#define RC    96           // R*C = 3*32

// d_out float offsets
#define OFF_NULLARY 0            // 16
#define OFF_UNARY   16           // 256
#define OFF_BINARY  272          // 3840
#define OFF_AK      4112         // 46080
#define OFF_OK      50192        // 96

// ws float offsets
#define WS_WT   0                // [NUM_IN][RC] = 15360
#define WS_VT   15360            // 15360
#define WS_OK   30720            // 96
#define WS_R01  30816            // rules r=0 [3840] then r=1 [3840]

// ---------------- Kernel 1: softmax(and_kernel) -> ak, w/v tables; sigmoid(or) -> ok
__global__ __launch_bounds__(256) void prep_kernel(
    const float* __restrict__ and_k,   // (R,C,NUM_IN,3) flat
    const float* __restrict__ or_k,    // (R,C) flat
    const float* __restrict__ temp,    // (1,)
    float* __restrict__ ak_out,        // d_out + OFF_AK
    float* __restrict__ ok_out,        // d_out + OFF_OK
    float* __restrict__ wt,            // ws: [i][rc]
    float* __restrict__ vt,            // ws: [i][rc]
    float* __restrict__ okw)           // ws: [rc]
{
    int gid = blockIdx.x * 256 + threadIdx.x;   // 0 .. 15359
    float tinv = 1.0f / temp[0];
    if (gid < RC * NUM_IN) {
        int i  = gid % NUM_IN;
        int rc = gid / NUM_IN;
        float a0 = and_k[gid * 3 + 0] * tinv;
        float a1 = and_k[gid * 3 + 1] * tinv;
        float a2 = and_k[gid * 3 + 2] * tinv;
        float m  = fmaxf(a0, fmaxf(a1, a2));
        float e0 = expf(a0 - m), e1 = expf(a1 - m), e2 = expf(a2 - m);
        float s  = 1.0f / (e0 + e1 + e2);
        float k0 = e0 * s, k1 = e1 * s, k2 = e2 * s;
        ak_out[gid * 3 + 0] = k0;
        ak_out[gid * 3 + 1] = k1;
        ak_out[gid * 3 + 2] = k2;
        wt[i * RC + rc] = k0 - k1;        // conj_eval = x*w + v
        vt[i * RC + rc] = k1 + k2;
    }
    if (gid < RC) {
        float o = 1.0f / (1.0f + expf(-or_k[gid] * tinv));
        ok_out[gid] = o;
        okw[gid]    = o;
    }
}

// ---------------- Kernel 2: main conjunct/disjunct computation, one block per (b,perm)
__global__ __launch_bounds__(128) void main_kernel(
    const float* __restrict__ nullary,  // (B,32)
    const float* __restrict__ unary,    // (B,16,32)
    const float* __restrict__ binary,   // (B,16,15,32)
    const float* __restrict__ wt,       // [i][rc]
    const float* __restrict__ vt,       // [i][rc]
    const float* __restrict__ okw,      // [rc]
    float* __restrict__ binary_out,     // d_out + OFF_BINARY, [3840]
    float* __restrict__ rules01)        // ws: r0[3840], r1[3840]
{
    int bp  = blockIdx.x;          // 0..3839
    int bt  = bp / NPERM;
    int p   = bp % NPERM;
    int a   = p / 15;
    int rem = p % 15;
    int b   = (rem < a) ? rem : rem + 1;
    int bprime = rem;                       // b - (b>a)
    int aprime = (a > b) ? a - 1 : a;

    __shared__ float xs[NUM_IN];
    int t = threadIdx.x;
    for (int idx = t; idx < NUM_IN; idx += 128) {
        int seg = idx >> 5, j = idx & 31;
        float v;
        if      (seg == 0) v = nullary[bt * 32 + j];
        else if (seg == 1) v = unary[(bt * 16 + a) * 32 + j];
        else if (seg == 2) v = unary[(bt * 16 + b) * 32 + j];
        else if (seg == 3) v = binary[((bt * 16 + a) * 15 + bprime) * 32 + j];
        else               v = binary[((bt * 16 + b) * 15 + aprime) * 32 + j];
        xs[idx] = v;
    }
    __syncthreads();

    if (t < RC) {
        const float* wrow = wt + t;
        const float* vrow = vt + t;
        float c0 = 1.0f, c1 = 1.0f, c2 = 1.0f, c3 = 1.0f;
        #pragma unroll 4
        for (int i = 0; i < NUM_IN; i += 4) {
            c0 *= fmaf(xs[i + 0], wrow[(i + 0) * RC], vrow[(i + 0) * RC]);
            c1 *= fmaf(xs[i + 1], wrow[(i + 1) * RC], vrow[(i + 1) * RC]);
            c2 *= fmaf(xs[i + 2], wrow[(i + 2) * RC], vrow[(i + 2) * RC]);
            c3 *= fmaf(xs[i + 3], wrow[(i + 3) * RC], vrow[(i + 3) * RC]);
        }
        float conj = (c0 * c1) * (c2 * c3);
        float d = 1.0f - conj * okw[t];
        // product over the 32 c-lanes of each r-group (lanes [r*32, r*32+31])
        #pragma unroll
        for (int off = 1; off < 32; off <<= 1)
            d *= __shfl_xor(d, off, 32);
        if ((t & 31) == 0) {
            int r = t >> 5;
            float dis = 1.0f - d;
            if (r == 2) binary_out[bp] = dis;            // binary_rules directly
            else        rules01[r * 3840 + bp] = dis;    // staged for finish_kernel
        }
    }
}

// ---------------- Kernel 3: probsum reductions for nullary (240->1) and unary (15->1)
__global__ __launch_bounds__(256) void finish_kernel(
    const float* __restrict__ rules01,   // ws
    float* __restrict__ nullary_out,     // d_out + OFF_NULLARY, [16]
    float* __restrict__ unary_out)       // d_out + OFF_UNARY, [256]
{
    int bt = blockIdx.x;    // 0..15
    int t  = threadIdx.x;
    const float* r0 = rules01;
    const float* r1 = rules01 + 3840;

    // unary: o1 = t/16, lane-in-group = t%16 covers the 15 o2 slots
    {
        int o1 = t >> 4, l = t & 15;
        float v = (l < 15) ? (1.0f - r1[bt * NPERM + o1 * 15 + l]) : 1.0f;
        #pragma unroll
        for (int off = 1; off < 16; off <<= 1)
            v *= __shfl_xor(v, off, 16);
        if (l == 0) unary_out[bt * 16 + o1] = 1.0f - v;
    }

    // nullary: product over all 240 perms
    {
        float v = (t < NPERM) ? (1.0f - r0[bt * NPERM + t]) : 1.0f;
        #pragma unroll
        for (int off = 1; off < 64; off <<= 1)
            v *= __shfl_xor(v, off, 64);
        __shared__ float wprod[4];
        if ((t & 63) == 0) wprod[t >> 6] = v;
        __syncthreads();
        if (t == 0)
            nullary_out[bt] = 1.0f - wprod[0] * wprod[1] * wprod[2] * wprod[3];
    }
}

extern "C" void kernel_launch(void* const* d_in, const int* in_sizes, int n_in,
                              void* d_out, int out_size, void* d_ws, size_t ws_size,
                              hipStream_t stream) {
    const float* nullary = (const float*)d_in[0];   // (16,32)
    const float* unary   = (const float*)d_in[1];   // (16,16,32)
    const float* binary  = (const float*)d_in[2];   // (16,16,15,32)
    const float* and_k   = (const float*)d_in[3];   // (3,32,160,3)
    const float* or_k    = (const float*)d_in[4];   // (3,32)
    const float* temp    = (const float*)d_in[5];   // (1,)

    float* out = (float*)d_out;
    float* ws  = (float*)d_ws;

    float* wt      = ws + WS_WT;
    float* vt      = ws + WS_VT;
    float* okw     = ws + WS_OK;
    float* rules01 = ws + WS_R01;

    prep_kernel<<<60, 256, 0, stream>>>(and_k, or_k, temp,
                                        out + OFF_AK, out + OFF_OK,
                                        wt, vt, okw);
    main_kernel<<<B_ * NPERM, 128, 0, stream>>>(nullary, unary, binary,
                                                wt, vt, okw,
                                                out + OFF_BINARY, rules01);
    finish_kernel<<<B_, 256, 0, stream>>>(rules01,
                                          out + OFF_NULLARY, out + OFF_UNARY);
}

// Round 2
// 85.413 us; speedup vs baseline: 1.0217x; 1.0217x over previous
//
#include <hip/hip_runtime.h>
#include <math.h>

// Problem constants
#define B_     16
#define O_     16
#define NPERM  240          // O*(O-1)
#define NUM_IN 160          // 32 + 2*32 + 2*32
#define NI4    40           // NUM_IN/4
#define RC     96           // R*C
#define BPB    4            // (b,perm) pairs per block in main kernel

// d_out float offsets
#define OFF_NULLARY 0            // 16
#define OFF_UNARY   16           // 256
#define OFF_BINARY  272          // 3840
#define OFF_AK      4112         // 46080
#define OFF_OK      50192        // 96

// ws float offsets
#define WS_WT   0                // transposed [rc][NUM_IN] = 15360
#define WS_VT   15360            // transposed [rc][NUM_IN] = 15360
#define WS_OK   30720            // 96
#define WS_R01  30816            // rules r=0 [3840] then r=1 [3840]

// ---------------- Kernel 1: softmax(and_kernel) -> ak + transposed w/v tables; sigmoid(or) -> ok
// gid = rc*NUM_IN + i  (matches and_kernel's (R,C,NUM_IN,3) layout and the
// transposed [rc][i] table layout directly -> fully coalesced writes)
__global__ __launch_bounds__(256) void prep_kernel(
    const float* __restrict__ and_k,   // (R,C,NUM_IN,3) flat
    const float* __restrict__ or_k,    // (R,C) flat
    const float* __restrict__ temp,    // (1,)
    float* __restrict__ ak_out,        // d_out + OFF_AK
    float* __restrict__ ok_out,        // d_out + OFF_OK
    float* __restrict__ wt,            // ws: [rc][i]
    float* __restrict__ vt,            // ws: [rc][i]
    float* __restrict__ okw)           // ws: [rc]
{
    int gid = blockIdx.x * 256 + threadIdx.x;   // 0 .. 15359
    float tinv = 1.0f / temp[0];
    if (gid < RC * NUM_IN) {
        float a0 = and_k[gid * 3 + 0] * tinv;
        float a1 = and_k[gid * 3 + 1] * tinv;
        float a2 = and_k[gid * 3 + 2] * tinv;
        float m  = fmaxf(a0, fmaxf(a1, a2));
        float e0 = __expf(a0 - m), e1 = __expf(a1 - m), e2 = __expf(a2 - m);
        float s  = 1.0f / (e0 + e1 + e2);
        float k0 = e0 * s, k1 = e1 * s, k2 = e2 * s;
        ak_out[gid * 3 + 0] = k0;
        ak_out[gid * 3 + 1] = k1;
        ak_out[gid * 3 + 2] = k2;
        wt[gid] = k0 - k1;        // conj_eval = x*w + v
        vt[gid] = k1 + k2;
    }
    if (gid < RC) {
        float o = 1.0f / (1.0f + __expf(-or_k[gid] * tinv));
        ok_out[gid] = o;
        okw[gid]    = o;
    }
}

// ---------------- Kernel 2: main conjunct/disjunct computation
// One block per BPB (b,perm) pairs. Lanes 0..95 own one rc each; table read
// as float4 along i (coalesced-ish rows, L2-resident); x broadcast from LDS.
__global__ __launch_bounds__(128) void main_kernel(
    const float* __restrict__ nullary,  // (B,32)
    const float* __restrict__ unary,    // (B,16,32)
    const float* __restrict__ binary,   // (B,16,15,32)
    const float* __restrict__ wt,       // ws: [rc][i]
    const float* __restrict__ vt,       // ws: [rc][i]
    const float* __restrict__ okw,      // ws: [rc]
    float* __restrict__ binary_out,     // d_out + OFF_BINARY, [3840]
    float* __restrict__ rules01)        // ws: r0[3840], r1[3840]
{
    int bp0 = blockIdx.x * BPB;
    __shared__ float xs[BPB * NUM_IN];

    int t = threadIdx.x;
    // Gather phase: 640 floats, 128 threads, 5 iterations, 32-float runs
    for (int idx = t; idx < BPB * NUM_IN; idx += 128) {
        int bpl = idx / NUM_IN;
        int i   = idx - bpl * NUM_IN;
        int bp  = bp0 + bpl;
        int bt  = bp / NPERM;
        int p   = bp - bt * NPERM;
        int a   = p / 15;
        int rem = p - a * 15;
        int b   = rem + (rem >= a);
        int bprime = rem;                 // b - (b > a)
        int aprime = a - (a > b);
        int seg = i >> 5, j = i & 31;
        float v;
        if      (seg == 0) v = nullary[bt * 32 + j];
        else if (seg == 1) v = unary[(bt * 16 + a) * 32 + j];
        else if (seg == 2) v = unary[(bt * 16 + b) * 32 + j];
        else if (seg == 3) v = binary[((bt * 16 + a) * 15 + bprime) * 32 + j];
        else               v = binary[((bt * 16 + b) * 15 + aprime) * 32 + j];
        xs[idx] = v;
    }
    __syncthreads();

    if (t < RC) {
        const float4* w4 = (const float4*)wt + t * NI4;
        const float4* v4 = (const float4*)vt + t * NI4;
        const float4* x4 = (const float4*)xs;           // [BPB][NI4]
        float cA[BPB], cB[BPB];
        #pragma unroll
        for (int l = 0; l < BPB; ++l) { cA[l] = 1.0f; cB[l] = 1.0f; }

        #pragma unroll 2
        for (int s = 0; s < NI4; ++s) {
            float4 w = w4[s];
            float4 v = v4[s];
            #pragma unroll
            for (int l = 0; l < BPB; ++l) {
                float4 x = x4[l * NI4 + s];             // LDS broadcast b128
                cA[l] *= fmaf(x.x, w.x, v.x);
                cB[l] *= fmaf(x.y, w.y, v.y);
                cA[l] *= fmaf(x.z, w.z, v.z);
                cB[l] *= fmaf(x.w, w.w, v.w);
            }
        }

        float o = okw[t];
        int r = t >> 5;
        #pragma unroll
        for (int l = 0; l < BPB; ++l) {
            float d = 1.0f - (cA[l] * cB[l]) * o;
            // product across the 32 c-lanes of this r-group
            #pragma unroll
            for (int off = 1; off < 32; off <<= 1)
                d *= __shfl_xor(d, off, 32);
            if ((t & 31) == 0) {
                float dis = 1.0f - d;
                int bp = bp0 + l;
                if (r == 2) binary_out[bp] = dis;
                else        rules01[r * (B_ * NPERM) + bp] = dis;
            }
        }
    }
}

// ---------------- Kernel 3: probsum reductions for nullary (240->1) and unary (15->1)
__global__ __launch_bounds__(256) void finish_kernel(
    const float* __restrict__ rules01,   // ws
    float* __restrict__ nullary_out,     // d_out + OFF_NULLARY, [16]
    float* __restrict__ unary_out)       // d_out + OFF_UNARY, [256]
{
    int bt = blockIdx.x;    // 0..15
    int t  = threadIdx.x;
    const float* r0 = rules01;
    const float* r1 = rules01 + B_ * NPERM;

    // unary: o1 = t/16, lane-in-group covers the 15 o2 slots
    {
        int o1 = t >> 4, l = t & 15;
        float v = (l < 15) ? (1.0f - r1[bt * NPERM + o1 * 15 + l]) : 1.0f;
        #pragma unroll
        for (int off = 1; off < 16; off <<= 1)
            v *= __shfl_xor(v, off, 16);
        if (l == 0) unary_out[bt * 16 + o1] = 1.0f - v;
    }

    // nullary: product over all 240 perms
    {
        float v = (t < NPERM) ? (1.0f - r0[bt * NPERM + t]) : 1.0f;
        #pragma unroll
        for (int off = 1; off < 64; off <<= 1)
            v *= __shfl_xor(v, off, 64);
        __shared__ float wprod[4];
        if ((t & 63) == 0) wprod[t >> 6] = v;
        __syncthreads();
        if (t == 0)
            nullary_out[bt] = 1.0f - wprod[0] * wprod[1] * wprod[2] * wprod[3];
    }
}

extern "C" void kernel_launch(void* const* d_in, const int* in_sizes, int n_in,
                              void* d_out, int out_size, void* d_ws, size_t ws_size,
                              hipStream_t stream) {
    const float* nullary = (const float*)d_in[0];   // (16,32)
    const float* unary   = (const float*)d_in[1];   // (16,16,32)
    const float* binary  = (const float*)d_in[2];   // (16,16,15,32)
    const float* and_k   = (const float*)d_in[3];   // (3,32,160,3)
    const float* or_k    = (const float*)d_in[4];   // (3,32)
    const float* temp    = (const float*)d_in[5];   // (1,)

    float* out = (float*)d_out;
    float* ws  = (float*)d_ws;

    float* wt      = ws + WS_WT;
    float* vt      = ws + WS_VT;
    float* okw     = ws + WS_OK;
    float* rules01 = ws + WS_R01;

    prep_kernel<<<60, 256, 0, stream>>>(and_k, or_k, temp,
                                        out + OFF_AK, out + OFF_OK,
                                        wt, vt, okw);
    main_kernel<<<(B_ * NPERM) / BPB, 128, 0, stream>>>(nullary, unary, binary,
                                                        wt, vt, okw,
                                                        out + OFF_BINARY, rules01);
    finish_kernel<<<B_, 256, 0, stream>>>(rules01,
                                          out + OFF_NULLARY, out + OFF_UNARY);
}